// Round 1
// baseline (71.926 us; speedup 1.0000x reference)
//
#include <hip/hip_runtime.h>

#define NB 64
#define NA 5
#define NC 20
#define NH 38
#define NW 38
#define MAXT 40
#define CELLS_PER_B (NA * NH * NW)   // 7220
#define CHUNKS 29                    // ceil(7220 / 256)

__constant__ float c_aw[NA] = {1.3221f, 3.19275f, 5.05587f, 9.47112f, 11.2364f};
__constant__ float c_ah[NA] = {1.73145f, 4.00944f, 8.09892f, 4.84053f, 10.0071f};

__device__ __forceinline__ float sl1(float d) {
    d = fabsf(d);
    return (d < 1.0f) ? 0.5f * d * d : d - 0.5f;
}

__global__ __launch_bounds__(256) void region_loss_kernel(
    const float* __restrict__ outp, const float* __restrict__ tgt,
    float* __restrict__ acc /* acc[0]=loss_box, acc[1]=loss_cls */)
{
    __shared__ float s_gx[MAXT], s_gy[MAXT], s_gw[MAXT], s_gh[MAXT];
    __shared__ int   s_bn[MAXT], s_gi[MAXT], s_gj[MAXT], s_cls[MAXT], s_valid[MAXT];

    const int b     = blockIdx.x / CHUNKS;
    const int chunk = blockIdx.x - b * CHUNKS;
    const int tid   = threadIdx.x;

    // ---- per-target prep (40 targets per batch) into LDS ----
    if (tid < MAXT) {
        const float* tb = tgt + (size_t)(b * MAXT + tid) * 5;
        // valid = cumprod(target[..,1] != 0) > 0  (all t' <= t nonzero)
        int valid = 1;
        for (int tp = 0; tp <= tid; ++tp) {
            if (tgt[(size_t)(b * MAXT + tp) * 5 + 1] == 0.0f) { valid = 0; break; }
        }
        float gx = tb[1] * (float)NW;
        float gy = tb[2] * (float)NH;
        float gw = tb[3] * (float)NW;
        float gh = tb[4] * (float)NH;
        // best anchor by wh-IoU, first-max-wins (jnp.argmax)
        int bn = 0; float best = -1.0f;
        #pragma unroll
        for (int a = 0; a < NA; ++a) {
            float inter = fminf(gw, c_aw[a]) * fminf(gh, c_ah[a]);
            float aiou  = inter / (gw * gh + c_aw[a] * c_ah[a] - inter);
            if (aiou > best) { best = aiou; bn = a; }
        }
        int gi = min(max((int)gx, 0), NW - 1);   // trunc-toward-zero == astype(int32) here
        int gj = min(max((int)gy, 0), NH - 1);
        s_gx[tid] = gx; s_gy[tid] = gy; s_gw[tid] = gw; s_gh[tid] = gh;
        s_bn[tid] = bn; s_gi[tid] = gi; s_gj[tid] = gj;
        s_cls[tid] = (int)tb[0]; s_valid[tid] = valid;
    }
    __syncthreads();

    float box_sum = 0.0f, cls_sum = 0.0f;
    const int c = chunk * 256 + tid;
    if (c < CELLS_PER_B) {
        const int a  = c / (NH * NW);
        const int r  = c - a * (NH * NW);
        const int j  = r / NW;
        const int i  = r - j * NW;
        const int cs = NH * NW;
        const float* cell = outp + (size_t)((b * NA + a) * (5 + NC)) * cs + r;

        const float xo = cell[0];
        const float yo = cell[cs];
        const float wo = cell[2 * cs];
        const float ho = cell[3 * cs];
        const float co = cell[4 * cs];

        const float sx = 1.0f / (1.0f + expf(-xo));
        const float sy = 1.0f / (1.0f + expf(-yo));
        const float sc = 1.0f / (1.0f + expf(-co));

        const float px = sx + (float)i;
        const float py = sy + (float)j;
        const float pw = expf(wo) * c_aw[a];
        const float ph = expf(ho) * c_ah[a];
        const float px1 = px - 0.5f * pw, px2 = px + 0.5f * pw;
        const float py1 = py - 0.5f * ph, py2 = py + 0.5f * ph;
        const float parea = pw * ph;

        // max IoU vs all valid GT boxes + winner (last matching t wins)
        float cur = 0.0f;
        int wt = -1;
        for (int t = 0; t < MAXT; ++t) {
            if (!s_valid[t]) continue;               // uniform branch
            const float gx = s_gx[t], gy = s_gy[t], gw = s_gw[t], gh = s_gh[t];
            float iw = fminf(px2, gx + 0.5f * gw) - fmaxf(px1, gx - 0.5f * gw);
            float ih = fminf(py2, gy + 0.5f * gh) - fmaxf(py1, gy - 0.5f * gh);
            iw = fmaxf(iw, 0.0f); ih = fmaxf(ih, 0.0f);
            const float inter = iw * ih;
            const float iou = inter / (gw * gh + parea - inter);
            cur = fmaxf(cur, iou);
            if ((s_bn[t] == a) & (s_gj[t] == j) & (s_gi[t] == i)) wt = t;
        }

        float cm    = (cur > 0.4f) ? 0.0f : 1.0f;    // NOOBJECT_SCALE = 1
        float tconf = 0.0f;

        if (wt >= 0) {
            cm = 5.0f;                                // OBJECT_SCALE
            const float gx = s_gx[wt], gy = s_gy[wt], gw = s_gw[wt], gh = s_gh[wt];
            float iw = fminf(px2, gx + 0.5f * gw) - fmaxf(px1, gx - 0.5f * gw);
            float ih = fminf(py2, gy + 0.5f * gh) - fmaxf(py1, gy - 0.5f * gh);
            iw = fmaxf(iw, 0.0f); ih = fmaxf(ih, 0.0f);
            const float inter = iw * ih;
            tconf = inter / (gw * gh + parea - inter);

            const float vtx = gx - (float)i;          // gi == i at winner cell
            const float vty = gy - (float)j;
            const float vtw = logf(gw / c_aw[a]);
            const float vth = logf(gh / c_ah[a]);
            box_sum += 0.5f * (sl1(sx - vtx) + sl1(sy - vty) + sl1(wo - vtw) + sl1(ho - vth));

            // focal class loss: -(1-pt)^2 * log_softmax(logits)[tcls]
            const int tci = s_cls[wt];
            float m = -1e30f, lt = 0.0f;
            #pragma unroll
            for (int q = 0; q < NC; ++q) {            // static indexing, no scratch
                const float v = cell[(5 + q) * cs];
                m = fmaxf(m, v);
                if (q == tci) lt = v;
            }
            float se = 0.0f;
            #pragma unroll
            for (int q = 0; q < NC; ++q) se += expf(cell[(5 + q) * cs] - m);
            const float logpt = lt - (m + logf(se));
            const float pt = expf(logpt);
            const float om = 1.0f - pt;
            cls_sum += -(om * om) * logpt;
        }
        const float dconf = sc - tconf;
        box_sum += 0.5f * cm * dconf * dconf;
    }

    // ---- block reduction: wave64 shfl + LDS across 4 waves ----
    #pragma unroll
    for (int off = 32; off > 0; off >>= 1) {
        box_sum += __shfl_down(box_sum, off);
        cls_sum += __shfl_down(cls_sum, off);
    }
    __shared__ float red[8];
    const int wv = tid >> 6, ln = tid & 63;
    if (ln == 0) { red[wv] = box_sum; red[4 + wv] = cls_sum; }
    __syncthreads();
    if (tid == 0) {
        atomicAdd(&acc[0], red[0] + red[1] + red[2] + red[3]);
        atomicAdd(&acc[1], red[4] + red[5] + red[6] + red[7]);
    }
}

__global__ void finalize_kernel(const float* __restrict__ acc, float* __restrict__ o)
{
    const float box = acc[0], cls = acc[1];
    o[0] = box + cls;   // loss
    o[1] = cls;         // loss_cls
    o[2] = box;         // loss_box
}

extern "C" void kernel_launch(void* const* d_in, const int* in_sizes, int n_in,
                              void* d_out, int out_size, void* d_ws, size_t ws_size,
                              hipStream_t stream)
{
    const float* outp = (const float*)d_in[0];
    const float* tgt  = (const float*)d_in[1];
    float* acc = (float*)d_ws;

    hipMemsetAsync(acc, 0, 2 * sizeof(float), stream);
    region_loss_kernel<<<dim3(NB * CHUNKS), dim3(256), 0, stream>>>(outp, tgt, acc);
    finalize_kernel<<<1, 1, 0, stream>>>(acc, (float*)d_out);
}

// Round 2
// 42.683 us; speedup vs baseline: 1.6851x; 1.6851x over previous
//
#include <hip/hip_runtime.h>

#define NB 64
#define NA 5
#define NC 20
#define NH 38
#define NW 38
#define MAXT 40
#define CS (NH * NW)                 // 1444
#define CELLS_PER_B (NA * CS)        // 7220
#define TPB 256
#define CPT 2                        // cells per thread
#define CHUNK_CELLS (TPB * CPT)      // 512
#define CHUNKS 15                    // ceil(7220 / 512)

__constant__ float c_aw[NA] = {1.3221f, 3.19275f, 5.05587f, 9.47112f, 11.2364f};
__constant__ float c_ah[NA] = {1.73145f, 4.00944f, 8.09892f, 4.84053f, 10.0071f};

__device__ __forceinline__ float sl1(float d) {
    d = fabsf(d);
    return (d < 1.0f) ? 0.5f * d * d : d - 0.5f;
}
__device__ __forceinline__ float sigm(float x) {
    return __builtin_amdgcn_rcpf(1.0f + __expf(-x));
}

__global__ __launch_bounds__(TPB) void region_loss_kernel(
    const float* __restrict__ outp, const float* __restrict__ tgt,
    float* __restrict__ acc /* acc[0]=loss_box, acc[1]=loss_cls */)
{
    __shared__ float4 s_box[MAXT];   // x1,y1,x2,y2
    __shared__ float4 s_vt[MAXT];    // vtx,vty,vtw,vth
    __shared__ float  s_ga04[MAXT];  // 0.4 * gw * gh
    __shared__ int    s_key[MAXT];   // a*1444 + gj*38 + gi, or -1
    __shared__ int    s_cls[MAXT];

    const int b     = blockIdx.x / CHUNKS;
    const int chunk = blockIdx.x - b * CHUNKS;
    const int tid   = threadIdx.x;

    // ---- per-target prep: wave 0, one lane per target, ballot for cumprod ----
    if (tid < 64) {
        const bool is_t = tid < MAXT;
        const float* tb = tgt + b * (MAXT * 5) + tid * 5;
        float t0 = 0.f, t1 = 0.f, t2 = 0.f, t3 = 0.f, t4 = 0.f;
        if (is_t) { t0 = tb[0]; t1 = tb[1]; t2 = tb[2]; t3 = tb[3]; t4 = tb[4]; }
        const unsigned long long nz = __ballot(is_t && (t1 != 0.0f));
        const bool valid = is_t && ((~nz & (((1ull << tid) << 1) - 1ull)) == 0ull);
        if (is_t) {
            if (valid) {
                const float gx = t1 * NW, gy = t2 * NH, gw = t3 * NW, gh = t4 * NH;
                int bn = 0; float best = -1.0f;
                #pragma unroll
                for (int a = 0; a < NA; ++a) {
                    const float inter = fminf(gw, c_aw[a]) * fminf(gh, c_ah[a]);
                    const float aiou  = inter / (gw * gh + c_aw[a] * c_ah[a] - inter);
                    if (aiou > best) { best = aiou; bn = a; }
                }
                const int gi = min(max((int)gx, 0), NW - 1);
                const int gj = min(max((int)gy, 0), NH - 1);
                s_box[tid]  = make_float4(gx - 0.5f * gw, gy - 0.5f * gh,
                                          gx + 0.5f * gw, gy + 0.5f * gh);
                s_vt[tid]   = make_float4(gx - (float)gi, gy - (float)gj,
                                          __logf(gw / c_aw[bn]), __logf(gh / c_ah[bn]));
                s_ga04[tid] = 0.4f * gw * gh;
                s_key[tid]  = bn * CS + gj * NW + gi;
                s_cls[tid]  = (int)t0;
            } else {
                s_box[tid]  = make_float4(3e30f, 3e30f, 3e30f, 3e30f); // inter -> 0
                s_vt[tid]   = make_float4(0.f, 0.f, 0.f, 0.f);
                s_ga04[tid] = 0.0f;
                s_key[tid]  = -1;
                s_cls[tid]  = 0;
            }
        }
    }
    __syncthreads();

    // ---- per-cell state (2 cells/thread, all indices compile-time) ----
    const int cbase = chunk * CHUNK_CELLS + tid;
    float box_sum = 0.0f, cls_sum = 0.0f;

    int   cc[CPT];  bool live[CPT], flag[CPT];  int wt[CPT];
    float sxv[CPT], syv[CPT], wov[CPT], hov[CPT], scv[CPT];
    float px1[CPT], px2[CPT], py1[CPT], py2[CPT], parea[CPT], p04[CPT];

    #pragma unroll
    for (int u = 0; u < CPT; ++u) {
        const int c = cbase + u * TPB;
        cc[u] = c; live[u] = (c < CELLS_PER_B); flag[u] = false; wt[u] = -1;
        if (live[u]) {
            const int a = c / CS, r = c - a * CS;
            const int j = r / NW,  i = r - j * NW;
            const float* cell = outp + (size_t)((b * NA + a) * (5 + NC)) * CS + r;
            const float xo = cell[0],     yo = cell[CS];
            const float w0 = cell[2*CS],  h0 = cell[3*CS], cv = cell[4*CS];
            sxv[u] = sigm(xo); syv[u] = sigm(yo); scv[u] = sigm(cv);
            wov[u] = w0; hov[u] = h0;
            const float pxc = sxv[u] + (float)i, pyc = syv[u] + (float)j;
            const float pw = __expf(w0) * c_aw[a], ph = __expf(h0) * c_ah[a];
            px1[u] = pxc - 0.5f * pw; px2[u] = pxc + 0.5f * pw;
            py1[u] = pyc - 0.5f * ph; py2[u] = pyc + 0.5f * ph;
            parea[u] = pw * ph; p04[u] = 0.4f * parea[u];
        } else {
            sxv[u]=syv[u]=wov[u]=hov[u]=scv[u]=0.f;
            px1[u]=px2[u]=py1[u]=py2[u]=0.f; parea[u]=p04[u]=0.f;
        }
    }

    // ---- hot loop: divide-free IoU-threshold test + winner key match ----
    #pragma unroll
    for (int t = 0; t < MAXT; ++t) {
        const float4 bx = s_box[t];
        const float  ga = s_ga04[t];
        const int    ky = s_key[t];
        #pragma unroll
        for (int u = 0; u < CPT; ++u) {
            const float iw = fminf(px2[u], bx.z) - fmaxf(px1[u], bx.x);
            const float ih = fminf(py2[u], bx.w) - fmaxf(py1[u], bx.y);
            const float inter = fmaxf(iw, 0.0f) * fmaxf(ih, 0.0f);
            // iou > 0.4  <=>  1.4*inter > 0.4*(garea + parea)
            flag[u] = flag[u] | (1.4f * inter > p04[u] + ga);
            if (ky == cc[u]) wt[u] = t;   // ascending t: last match wins
        }
    }

    // ---- epilogue per cell ----
    #pragma unroll
    for (int u = 0; u < CPT; ++u) {
        if (!live[u]) continue;
        float cm = flag[u] ? 0.0f : 1.0f;   // NOOBJECT_SCALE = 1
        float tconf = 0.0f;
        if (wt[u] >= 0) {
            cm = 5.0f;                       // OBJECT_SCALE
            const int t = wt[u];
            const float4 bx = s_box[t];      // runtime index into LDS: fine
            const float iw = fminf(px2[u], bx.z) - fmaxf(px1[u], bx.x);
            const float ih = fminf(py2[u], bx.w) - fmaxf(py1[u], bx.y);
            const float inter = fmaxf(iw, 0.f) * fmaxf(ih, 0.f);
            const float garea = s_ga04[t] * 2.5f;
            tconf = inter / (garea + parea[u] - inter);   // exact div, rare path
            const float4 vt = s_vt[t];
            box_sum += 0.5f * (sl1(sxv[u] - vt.x) + sl1(syv[u] - vt.y) +
                               sl1(wov[u] - vt.z) + sl1(hov[u] - vt.w));
            // focal class loss
            const int c = cc[u];
            const int a = c / CS, r = c - a * CS;
            const float* cell = outp + (size_t)((b * NA + a) * (5 + NC)) * CS + r;
            const int tci = s_cls[t];
            float m = -1e30f, lt = 0.0f;
            #pragma unroll
            for (int q = 0; q < NC; ++q) {
                const float v = cell[(5 + q) * CS];
                m = fmaxf(m, v);
                if (q == tci) lt = v;
            }
            float se = 0.0f;
            #pragma unroll
            for (int q = 0; q < NC; ++q) se += __expf(cell[(5 + q) * CS] - m);
            const float logpt = lt - (m + __logf(se));
            const float pt = __expf(logpt);
            const float om = 1.0f - pt;
            cls_sum += -(om * om) * logpt;
        }
        const float dconf = scv[u] - tconf;
        box_sum += 0.5f * cm * dconf * dconf;
    }

    // ---- block reduction ----
    #pragma unroll
    for (int off = 32; off > 0; off >>= 1) {
        box_sum += __shfl_down(box_sum, off);
        cls_sum += __shfl_down(cls_sum, off);
    }
    __shared__ float red[8];
    const int wv = tid >> 6, ln = tid & 63;
    if (ln == 0) { red[wv] = box_sum; red[4 + wv] = cls_sum; }
    __syncthreads();
    if (tid == 0) {
        atomicAdd(&acc[0], red[0] + red[1] + red[2] + red[3]);
        atomicAdd(&acc[1], red[4] + red[5] + red[6] + red[7]);
    }
}

__global__ void finalize_kernel(const float* __restrict__ acc, float* __restrict__ o)
{
    const float box = acc[0], cls = acc[1];
    o[0] = box + cls;   // loss
    o[1] = cls;         // loss_cls
    o[2] = box;         // loss_box
}

extern "C" void kernel_launch(void* const* d_in, const int* in_sizes, int n_in,
                              void* d_out, int out_size, void* d_ws, size_t ws_size,
                              hipStream_t stream)
{
    const float* outp = (const float*)d_in[0];
    const float* tgt  = (const float*)d_in[1];
    float* acc = (float*)d_ws;

    hipMemsetAsync(acc, 0, 2 * sizeof(float), stream);
    region_loss_kernel<<<dim3(NB * CHUNKS), dim3(TPB), 0, stream>>>(outp, tgt, acc);
    finalize_kernel<<<1, 1, 0, stream>>>(acc, (float*)d_out);
}

// Round 3
// 33.670 us; speedup vs baseline: 2.1362x; 1.2677x over previous
//
#include <hip/hip_runtime.h>

#define NB 64
#define NA 5
#define NC 20
#define NH 38
#define NW 38
#define MAXT 40
#define CS (NH * NW)                 // 1444
#define CELLS_PER_B (NA * CS)        // 7220
#define TPB 256
#define CPT 2                        // cells per thread
#define CHUNK_CELLS (TPB * CPT)      // 512
#define CHUNKS 15                    // ceil(7220 / 512)
#define NPART (NB * CHUNKS)          // 960 partial-sum slots

__constant__ float c_aw[NA] = {1.3221f, 3.19275f, 5.05587f, 9.47112f, 11.2364f};
__constant__ float c_ah[NA] = {1.73145f, 4.00944f, 8.09892f, 4.84053f, 10.0071f};

__device__ __forceinline__ float sl1(float d) {
    d = fabsf(d);
    return (d < 1.0f) ? 0.5f * d * d : d - 0.5f;
}
__device__ __forceinline__ float sigm(float x) {
    return __builtin_amdgcn_rcpf(1.0f + __expf(-x));
}

__global__ __launch_bounds__(TPB) void region_loss_kernel(
    const float* __restrict__ outp, const float* __restrict__ tgt,
    float2* __restrict__ partials /* one {box,cls} per block, always written */)
{
    __shared__ float4 s_box[MAXT];   // x1,y1,x2,y2
    __shared__ float4 s_vt[MAXT];    // vtx,vty,vtw,vth
    __shared__ float  s_ga04[MAXT];  // 0.4 * gw * gh
    __shared__ int    s_key[MAXT];   // a*1444 + gj*38 + gi, or -1
    __shared__ int    s_cls[MAXT];

    const int b     = blockIdx.x / CHUNKS;
    const int chunk = blockIdx.x - b * CHUNKS;
    const int tid   = threadIdx.x;

    // ---- per-target prep: wave 0, one lane per target, ballot for cumprod ----
    if (tid < 64) {
        const bool is_t = tid < MAXT;
        const float* tb = tgt + b * (MAXT * 5) + tid * 5;
        float t0 = 0.f, t1 = 0.f, t2 = 0.f, t3 = 0.f, t4 = 0.f;
        if (is_t) { t0 = tb[0]; t1 = tb[1]; t2 = tb[2]; t3 = tb[3]; t4 = tb[4]; }
        const unsigned long long nz = __ballot(is_t && (t1 != 0.0f));
        const bool valid = is_t && ((~nz & (((1ull << tid) << 1) - 1ull)) == 0ull);
        if (is_t) {
            if (valid) {
                const float gx = t1 * NW, gy = t2 * NH, gw = t3 * NW, gh = t4 * NH;
                int bn = 0; float best = -1.0f;
                #pragma unroll
                for (int a = 0; a < NA; ++a) {
                    const float inter = fminf(gw, c_aw[a]) * fminf(gh, c_ah[a]);
                    const float aiou  = inter / (gw * gh + c_aw[a] * c_ah[a] - inter);
                    if (aiou > best) { best = aiou; bn = a; }
                }
                const int gi = min(max((int)gx, 0), NW - 1);
                const int gj = min(max((int)gy, 0), NH - 1);
                s_box[tid]  = make_float4(gx - 0.5f * gw, gy - 0.5f * gh,
                                          gx + 0.5f * gw, gy + 0.5f * gh);
                s_vt[tid]   = make_float4(gx - (float)gi, gy - (float)gj,
                                          __logf(gw / c_aw[bn]), __logf(gh / c_ah[bn]));
                s_ga04[tid] = 0.4f * gw * gh;
                s_key[tid]  = bn * CS + gj * NW + gi;
                s_cls[tid]  = (int)t0;
            } else {
                s_box[tid]  = make_float4(3e30f, 3e30f, 3e30f, 3e30f); // inter -> 0
                s_vt[tid]   = make_float4(0.f, 0.f, 0.f, 0.f);
                s_ga04[tid] = 0.0f;
                s_key[tid]  = -1;
                s_cls[tid]  = 0;
            }
        }
    }
    __syncthreads();

    // ---- per-cell state (2 cells/thread, all indices compile-time) ----
    const int cbase = chunk * CHUNK_CELLS + tid;
    float box_sum = 0.0f, cls_sum = 0.0f;

    int   cc[CPT];  bool live[CPT], flag[CPT];  int wt[CPT];
    float sxv[CPT], syv[CPT], wov[CPT], hov[CPT], scv[CPT];
    float px1[CPT], px2[CPT], py1[CPT], py2[CPT], parea[CPT], p04[CPT];

    #pragma unroll
    for (int u = 0; u < CPT; ++u) {
        const int c = cbase + u * TPB;
        cc[u] = c; live[u] = (c < CELLS_PER_B); flag[u] = false; wt[u] = -1;
        if (live[u]) {
            const int a = c / CS, r = c - a * CS;
            const int j = r / NW,  i = r - j * NW;
            const float* cell = outp + (size_t)((b * NA + a) * (5 + NC)) * CS + r;
            const float xo = cell[0],     yo = cell[CS];
            const float w0 = cell[2*CS],  h0 = cell[3*CS], cv = cell[4*CS];
            sxv[u] = sigm(xo); syv[u] = sigm(yo); scv[u] = sigm(cv);
            wov[u] = w0; hov[u] = h0;
            const float pxc = sxv[u] + (float)i, pyc = syv[u] + (float)j;
            const float pw = __expf(w0) * c_aw[a], ph = __expf(h0) * c_ah[a];
            px1[u] = pxc - 0.5f * pw; px2[u] = pxc + 0.5f * pw;
            py1[u] = pyc - 0.5f * ph; py2[u] = pyc + 0.5f * ph;
            parea[u] = pw * ph; p04[u] = 0.4f * parea[u];
        } else {
            sxv[u]=syv[u]=wov[u]=hov[u]=scv[u]=0.f;
            px1[u]=px2[u]=py1[u]=py2[u]=0.f; parea[u]=p04[u]=0.f;
        }
    }

    // ---- hot loop: divide-free IoU-threshold test + winner key match ----
    #pragma unroll
    for (int t = 0; t < MAXT; ++t) {
        const float4 bx = s_box[t];
        const float  ga = s_ga04[t];
        const int    ky = s_key[t];
        #pragma unroll
        for (int u = 0; u < CPT; ++u) {
            const float iw = fminf(px2[u], bx.z) - fmaxf(px1[u], bx.x);
            const float ih = fminf(py2[u], bx.w) - fmaxf(py1[u], bx.y);
            const float inter = fmaxf(iw, 0.0f) * fmaxf(ih, 0.0f);
            // iou > 0.4  <=>  1.4*inter > 0.4*(garea + parea)
            flag[u] = flag[u] | (1.4f * inter > p04[u] + ga);
            if (ky == cc[u]) wt[u] = t;   // ascending t: last match wins
        }
    }

    // ---- epilogue per cell ----
    #pragma unroll
    for (int u = 0; u < CPT; ++u) {
        if (!live[u]) continue;
        float cm = flag[u] ? 0.0f : 1.0f;   // NOOBJECT_SCALE = 1
        float tconf = 0.0f;
        if (wt[u] >= 0) {
            cm = 5.0f;                       // OBJECT_SCALE
            const int t = wt[u];
            const float4 bx = s_box[t];      // runtime index into LDS: fine
            const float iw = fminf(px2[u], bx.z) - fmaxf(px1[u], bx.x);
            const float ih = fminf(py2[u], bx.w) - fmaxf(py1[u], bx.y);
            const float inter = fmaxf(iw, 0.f) * fmaxf(ih, 0.f);
            const float garea = s_ga04[t] * 2.5f;
            tconf = inter / (garea + parea[u] - inter);   // exact div, rare path
            const float4 vt = s_vt[t];
            box_sum += 0.5f * (sl1(sxv[u] - vt.x) + sl1(syv[u] - vt.y) +
                               sl1(wov[u] - vt.z) + sl1(hov[u] - vt.w));
            // focal class loss
            const int c = cc[u];
            const int a = c / CS, r = c - a * CS;
            const float* cell = outp + (size_t)((b * NA + a) * (5 + NC)) * CS + r;
            const int tci = s_cls[t];
            float m = -1e30f, lt = 0.0f;
            #pragma unroll
            for (int q = 0; q < NC; ++q) {
                const float v = cell[(5 + q) * CS];
                m = fmaxf(m, v);
                if (q == tci) lt = v;
            }
            float se = 0.0f;
            #pragma unroll
            for (int q = 0; q < NC; ++q) se += __expf(cell[(5 + q) * CS] - m);
            const float logpt = lt - (m + __logf(se));
            const float pt = __expf(logpt);
            const float om = 1.0f - pt;
            cls_sum += -(om * om) * logpt;
        }
        const float dconf = scv[u] - tconf;
        box_sum += 0.5f * cm * dconf * dconf;
    }

    // ---- block reduction -> one float2 per block (no atomics, no memset) ----
    #pragma unroll
    for (int off = 32; off > 0; off >>= 1) {
        box_sum += __shfl_down(box_sum, off);
        cls_sum += __shfl_down(cls_sum, off);
    }
    __shared__ float red[8];
    const int wv = tid >> 6, ln = tid & 63;
    if (ln == 0) { red[wv] = box_sum; red[4 + wv] = cls_sum; }
    __syncthreads();
    if (tid == 0) {
        partials[blockIdx.x] = make_float2(red[0] + red[1] + red[2] + red[3],
                                           red[4] + red[5] + red[6] + red[7]);
    }
}

__global__ __launch_bounds__(256) void finalize_kernel(
    const float2* __restrict__ partials, float* __restrict__ o)
{
    const int tid = threadIdx.x;
    float box = 0.0f, cls = 0.0f;
    for (int k = tid; k < NPART; k += 256) {
        const float2 p = partials[k];
        box += p.x; cls += p.y;
    }
    #pragma unroll
    for (int off = 32; off > 0; off >>= 1) {
        box += __shfl_down(box, off);
        cls += __shfl_down(cls, off);
    }
    __shared__ float red[8];
    const int wv = tid >> 6, ln = tid & 63;
    if (ln == 0) { red[wv] = box; red[4 + wv] = cls; }
    __syncthreads();
    if (tid == 0) {
        const float boxT = red[0] + red[1] + red[2] + red[3];
        const float clsT = red[4] + red[5] + red[6] + red[7];
        o[0] = boxT + clsT;   // loss
        o[1] = clsT;          // loss_cls
        o[2] = boxT;          // loss_box
    }
}

extern "C" void kernel_launch(void* const* d_in, const int* in_sizes, int n_in,
                              void* d_out, int out_size, void* d_ws, size_t ws_size,
                              hipStream_t stream)
{
    const float* outp = (const float*)d_in[0];
    const float* tgt  = (const float*)d_in[1];
    float2* partials = (float2*)d_ws;

    region_loss_kernel<<<dim3(NPART), dim3(TPB), 0, stream>>>(outp, tgt, partials);
    finalize_kernel<<<1, 256, 0, stream>>>(partials, (float*)d_out);
}

// Round 4
// 19.927 us; speedup vs baseline: 3.6094x; 1.6896x over previous
//
#include <hip/hip_runtime.h>

#define NB 64
#define NA 5
#define NC 20
#define NH 38
#define NW 38
#define MAXT 40
#define CS (NH * NW)                 // 1444
#define CELLS_PER_B (NA * CS)        // 7220
#define TPB 256
#define CPT 2                        // cells per thread
#define CHUNK_CELLS (TPB * CPT)      // 512
#define CHUNKS 15                    // ceil(7220 / 512)
#define NPART (NB * CHUNKS)          // 960

__constant__ float c_aw[NA] = {1.3221f, 3.19275f, 5.05587f, 9.47112f, 11.2364f};
__constant__ float c_ah[NA] = {1.73145f, 4.00944f, 8.09892f, 4.84053f, 10.0071f};

__device__ __forceinline__ float sl1(float d) {
    d = fabsf(d);
    return (d < 1.0f) ? 0.5f * d * d : d - 0.5f;
}
__device__ __forceinline__ float sigm(float x) {
    return __builtin_amdgcn_rcpf(1.0f + __expf(-x));
}

__global__ __launch_bounds__(TPB) void region_loss_kernel(
    const float* __restrict__ outp, const float* __restrict__ tgt,
    float2* __restrict__ partials)
{
    __shared__ float4 s_box[MAXT];   // gt x1,y1,x2,y2
    __shared__ float  s_ga04[MAXT];  // 0.4 * gw * gh
    __shared__ int    s_key[MAXT];   // bn*CS + gj*NW + gi, or -1

    const int b     = blockIdx.x / CHUNKS;
    const int chunk = blockIdx.x - b * CHUNKS;
    const int tid   = threadIdx.x;

    // private copies for the winner pass (wave 0 lanes)
    float w_gx = 0.f, w_gy = 0.f, w_gw = 0.f, w_gh = 0.f;
    int   w_bn = 0, w_gi = 0, w_gj = 0, w_cls = 0;
    bool  w_valid = false;

    // ---- per-target prep: wave 0, one lane per target, ballot for cumprod ----
    if (tid < 64) {
        const bool is_t = tid < MAXT;
        const float* tb = tgt + b * (MAXT * 5) + tid * 5;
        float t0 = 0.f, t1 = 0.f, t2 = 0.f, t3 = 0.f, t4 = 0.f;
        if (is_t) { t0 = tb[0]; t1 = tb[1]; t2 = tb[2]; t3 = tb[3]; t4 = tb[4]; }
        const unsigned long long nz = __ballot(is_t && (t1 != 0.0f));
        const bool valid = is_t && ((~nz & (((1ull << tid) << 1) - 1ull)) == 0ull);
        if (is_t) {
            if (valid) {
                const float gx = t1 * NW, gy = t2 * NH, gw = t3 * NW, gh = t4 * NH;
                int bn = 0; float best = -1.0f;
                #pragma unroll
                for (int a = 0; a < NA; ++a) {
                    const float inter = fminf(gw, c_aw[a]) * fminf(gh, c_ah[a]);
                    const float aiou  = inter / (gw * gh + c_aw[a] * c_ah[a] - inter);
                    if (aiou > best) { best = aiou; bn = a; }
                }
                const int gi = min(max((int)gx, 0), NW - 1);
                const int gj = min(max((int)gy, 0), NH - 1);
                s_box[tid]  = make_float4(gx - 0.5f * gw, gy - 0.5f * gh,
                                          gx + 0.5f * gw, gy + 0.5f * gh);
                s_ga04[tid] = 0.4f * gw * gh;
                s_key[tid]  = bn * CS + gj * NW + gi;
                w_gx = gx; w_gy = gy; w_gw = gw; w_gh = gh;
                w_bn = bn; w_gi = gi; w_gj = gj; w_cls = (int)t0; w_valid = true;
            } else {
                s_box[tid]  = make_float4(3e30f, 3e30f, -3e30f, -3e30f); // inter -> 0
                s_ga04[tid] = 0.0f;
                s_key[tid]  = -1;
            }
        }
    }
    __syncthreads();

    float box_sum = 0.0f, cls_sum = 0.0f;

    // ---- winner pass: only chunk==0 blocks, wave 0, <=40 lanes ----
    if (chunk == 0 && w_valid) {
        const int mykey = w_bn * CS + w_gj * NW + w_gi;
        bool last = true;
        for (int tp = tid + 1; tp < MAXT; ++tp) last &= (s_key[tp] != mykey);
        if (last) {
            const float* cell = outp + (size_t)((b * NA + w_bn) * (5 + NC)) * CS
                                + (w_gj * NW + w_gi);
            const float xo = cell[0],      yo = cell[CS];
            const float wo = cell[2 * CS], ho = cell[3 * CS], co = cell[4 * CS];
            float cls_v[NC];
            #pragma unroll
            for (int q = 0; q < NC; ++q) cls_v[q] = cell[(5 + q) * CS];

            const float sx = sigm(xo), sy = sigm(yo), sc = sigm(co);
            const float pxc = sx + (float)w_gi, pyc = sy + (float)w_gj;
            const float pw = __expf(wo) * c_aw[w_bn], ph = __expf(ho) * c_ah[w_bn];
            const float px1 = pxc - 0.5f * pw, px2 = pxc + 0.5f * pw;
            const float py1 = pyc - 0.5f * ph, py2 = pyc + 0.5f * ph;
            const float pa = pw * ph, p04 = 0.4f * pa;

            // flag exactly as the dense thread computes it (same formula/order)
            bool flag = false;
            for (int t = 0; t < MAXT; ++t) {
                const float4 bx = s_box[t];
                const float iw = fminf(px2, bx.z) - fmaxf(px1, bx.x);
                const float ih = fminf(py2, bx.w) - fmaxf(py1, bx.y);
                const float inter = fmaxf(iw, 0.0f) * fmaxf(ih, 0.0f);
                flag = flag | (1.4f * inter > p04 + s_ga04[t]);
            }
            const float cmd = flag ? 0.0f : 1.0f;

            // tconf = IoU(own gt box, pred box), exact divide
            const float gx1 = w_gx - 0.5f * w_gw, gx2 = w_gx + 0.5f * w_gw;
            const float gy1 = w_gy - 0.5f * w_gh, gy2 = w_gy + 0.5f * w_gh;
            const float iw = fminf(px2, gx2) - fmaxf(px1, gx1);
            const float ih = fminf(py2, gy2) - fmaxf(py1, gy1);
            const float inter = fmaxf(iw, 0.f) * fmaxf(ih, 0.f);
            const float tconf = inter / (w_gw * w_gh + pa - inter);

            // conf correction: winner term minus what the dense pass adds
            const float dc = sc - tconf;
            box_sum += 2.5f * dc * dc - 0.5f * cmd * sc * sc;

            // box smooth-L1
            const float vtx = w_gx - (float)w_gi, vty = w_gy - (float)w_gj;
            const float vtw = __logf(w_gw / c_aw[w_bn]);
            const float vth = __logf(w_gh / c_ah[w_bn]);
            box_sum += 0.5f * (sl1(sx - vtx) + sl1(sy - vty) +
                               sl1(wo - vtw) + sl1(ho - vth));

            // focal class loss
            float m = -1e30f;
            #pragma unroll
            for (int q = 0; q < NC; ++q) m = fmaxf(m, cls_v[q]);
            float se = 0.f, lt = 0.f;
            #pragma unroll
            for (int q = 0; q < NC; ++q) {
                se += __expf(cls_v[q] - m);
                if (q == w_cls) lt = cls_v[q];
            }
            const float logpt = lt - (m + __logf(se));
            const float pt = __expf(logpt);
            const float om = 1.0f - pt;
            cls_sum += -(om * om) * logpt;
        }
    }

    // ---- dense pass: 2 cells/thread, no winner logic, no divergence ----
    const int cbase = chunk * CHUNK_CELLS + tid;
    float px1[CPT], px2[CPT], py1[CPT], py2[CPT], p04[CPT], scv[CPT];
    bool  flag[CPT];

    #pragma unroll
    for (int u = 0; u < CPT; ++u) {
        const int c = cbase + u * TPB;
        flag[u] = false;
        if (c < CELLS_PER_B) {
            const int a = c / CS, r = c - a * CS;
            const int j = r / NW,  i = r - j * NW;
            const float* cell = outp + (size_t)((b * NA + a) * (5 + NC)) * CS + r;
            const float xo = cell[0],      yo = cell[CS];
            const float wo = cell[2 * CS], ho = cell[3 * CS], co = cell[4 * CS];
            const float sx = sigm(xo), sy = sigm(yo);
            scv[u] = sigm(co);
            const float pxc = sx + (float)i, pyc = sy + (float)j;
            const float pw = __expf(wo) * c_aw[a], ph = __expf(ho) * c_ah[a];
            px1[u] = pxc - 0.5f * pw; px2[u] = pxc + 0.5f * pw;
            py1[u] = pyc - 0.5f * ph; py2[u] = pyc + 0.5f * ph;
            p04[u] = 0.4f * (pw * ph);
        } else {
            px1[u] = 3e30f; px2[u] = -3e30f;   // inter -> 0, flag stays false
            py1[u] = 3e30f; py2[u] = -3e30f;
            p04[u] = 0.0f;  scv[u] = 0.0f;     // contribution -> 0
        }
    }

    #pragma unroll
    for (int t = 0; t < MAXT; ++t) {
        const float4 bx = s_box[t];
        const float  ga = s_ga04[t];
        #pragma unroll
        for (int u = 0; u < CPT; ++u) {
            const float iw = fminf(px2[u], bx.z) - fmaxf(px1[u], bx.x);
            const float ih = fminf(py2[u], bx.w) - fmaxf(py1[u], bx.y);
            const float inter = fmaxf(iw, 0.0f) * fmaxf(ih, 0.0f);
            flag[u] = flag[u] | (1.4f * inter > p04[u] + ga);
        }
    }

    #pragma unroll
    for (int u = 0; u < CPT; ++u) {
        const float cm = flag[u] ? 0.0f : 1.0f;
        box_sum += 0.5f * cm * scv[u] * scv[u];
    }

    // ---- block reduction -> one float2 per block ----
    #pragma unroll
    for (int off = 32; off > 0; off >>= 1) {
        box_sum += __shfl_down(box_sum, off);
        cls_sum += __shfl_down(cls_sum, off);
    }
    __shared__ float red[8];
    const int wv = tid >> 6, ln = tid & 63;
    if (ln == 0) { red[wv] = box_sum; red[4 + wv] = cls_sum; }
    __syncthreads();
    if (tid == 0) {
        partials[blockIdx.x] = make_float2(red[0] + red[1] + red[2] + red[3],
                                           red[4] + red[5] + red[6] + red[7]);
    }
}

__global__ __launch_bounds__(256) void finalize_kernel(
    const float2* __restrict__ partials, float* __restrict__ o)
{
    const int tid = threadIdx.x;
    float box = 0.0f, cls = 0.0f;
    for (int k = tid; k < NPART; k += 256) {
        const float2 p = partials[k];
        box += p.x; cls += p.y;
    }
    #pragma unroll
    for (int off = 32; off > 0; off >>= 1) {
        box += __shfl_down(box, off);
        cls += __shfl_down(cls, off);
    }
    __shared__ float red[8];
    const int wv = tid >> 6, ln = tid & 63;
    if (ln == 0) { red[wv] = box; red[4 + wv] = cls; }
    __syncthreads();
    if (tid == 0) {
        const float boxT = red[0] + red[1] + red[2] + red[3];
        const float clsT = red[4] + red[5] + red[6] + red[7];
        o[0] = boxT + clsT;   // loss
        o[1] = clsT;          // loss_cls
        o[2] = boxT;          // loss_box
    }
}

extern "C" void kernel_launch(void* const* d_in, const int* in_sizes, int n_in,
                              void* d_out, int out_size, void* d_ws, size_t ws_size,
                              hipStream_t stream)
{
    const float* outp = (const float*)d_in[0];
    const float* tgt  = (const float*)d_in[1];
    float2* partials = (float2*)d_ws;

    region_loss_kernel<<<dim3(NPART), dim3(TPB), 0, stream>>>(outp, tgt, partials);
    finalize_kernel<<<1, 256, 0, stream>>>(partials, (float*)d_out);
}